// Round 5
// baseline (191.318 us; speedup 1.0000x reference)
//
#include <hip/hip_runtime.h>
#include <hip/hip_bf16.h>
#include <stdint.h>

// ---------- common types / helpers ----------
typedef __attribute__((ext_vector_type(8))) short short8;   // 8 bf16 = 4 VGPR (MFMA A/B frag)
typedef __attribute__((ext_vector_type(4))) float f32x4;    // MFMA C/D frag
typedef __attribute__((ext_vector_type(4))) float f4;
typedef __attribute__((ext_vector_type(4))) short s4;

typedef __attribute__((address_space(1))) const void gvoid_t;
typedef __attribute__((address_space(3))) void lvoid_t;

__device__ __forceinline__ void gload_lds16(const void* g, void* l) {
  __builtin_amdgcn_global_load_lds((gvoid_t*)g, (lvoid_t*)l, 16, 0, 0);
}

__device__ __forceinline__ ushort f2b(float f) {  // f32 -> bf16 RNE
  union { float f; uint32_t u; } v; v.f = f;
  return (ushort)((v.u + 0x7fffu + ((v.u >> 16) & 1u)) >> 16);
}
__device__ __forceinline__ float b2f(ushort b) {
  union { uint32_t u; float f; } v; v.u = ((uint32_t)b) << 16;
  return v.f;
}

template <int N> __device__ __forceinline__ void wait_vmcnt();
template <> __device__ __forceinline__ void wait_vmcnt<0>() { asm volatile("s_waitcnt vmcnt(0)" ::: "memory"); }

__device__ __forceinline__ void wait_lgkm0() {
  asm volatile("s_waitcnt lgkmcnt(0)" ::: "memory");
  __builtin_amdgcn_sched_barrier(0);   // rule #18: keep MFMA below the wait
}

// ---------- f32 -> bf16 cast kernel ----------
__global__ void cvt_kernel(const float* __restrict__ in, ushort* __restrict__ out, int n4) {
  int i = blockIdx.x * 256 + threadIdx.x;
  if (i < n4) {
    f4 v = ((const f4*)in)[i];
    s4 o;
    o.x = (short)f2b(v.x); o.y = (short)f2b(v.y);
    o.z = (short)f2b(v.z); o.w = (short)f2b(v.w);
    ((s4*)out)[i] = o;
  }
}

// ---------- bf16 GEMM v4: C[M,N] = A[M,K] @ B[N,K]^T ----------
// BM=128, BK=32, 256 threads (4 waves 2Mx2N). Double-buffered LDS (40/32 KB)
// -> 3 blocks/CU resident; grid = 64*(N/BN) = 768 = 3/CU exact, XCD-owned bm.
// Swizzle: stage source chunk kc = (l&3)^((l>>3)&3) (LDS linear); frag reads at
// physical chunk kh ^ ((r16>>1)&3)  => <=2-way LDS conflicts (free).
template <int BN, typename OutT>
__global__ __launch_bounds__(256, 3) void gemm4(const ushort* __restrict__ A,
                                                const ushort* __restrict__ B,
                                                OutT* __restrict__ C,
                                                int N, int K) {
  constexpr int NF = BN / 32;       // n-frags per wave (wave tile 64 x BN/2)
  constexpr int HB = BN / 2;        // wave n-extent
  constexpr int BI = BN / 64;       // B stage rounds (per-thread gloads)

  __shared__ ushort As[2][128 * 32];
  __shared__ ushort Bs[2][BN * 32];

  const int tid = threadIdx.x;
  const int l = tid & 63, w = tid >> 6;
  const int wr = w >> 1, wc = w & 1;      // 2M x 2N
  const int r16 = l & 15, kh = l >> 4;
  const int kc = (l & 3) ^ ((l >> 3) & 3);   // pre-swizzled source chunk
  const int srow = w * 16 + (l >> 2);        // staging row within a 64-row group
  const int ksw = (r16 >> 1) & 3;            // read-side chunk swizzle

  const int xcd = blockIdx.x & 7;
  const int ii = blockIdx.x >> 3;
  const int bm = xcd * 8 + (ii & 7);         // XCD owns 8 contiguous A panels
  const int bn = ii >> 3;
  const ushort* Ag = A + (size_t)bm * 128 * K;
  const ushort* Bg = B + (size_t)bn * BN * K;
  const int NT = K >> 5;

  // prologue: stage tile 0 -> buf0
#pragma unroll
  for (int i = 0; i < 2; ++i)
    gload_lds16(Ag + (size_t)(i * 64 + srow) * K + kc * 8, &As[0][i * 2048 + w * 512]);
#pragma unroll
  for (int i = 0; i < BI; ++i)
    gload_lds16(Bg + (size_t)(i * 64 + srow) * K + kc * 8, &Bs[0][i * 2048 + w * 512]);
  wait_vmcnt<0>();
  __builtin_amdgcn_s_barrier();

  f32x4 acc[4][NF] = {};

  for (int u = 0; u < NT; ++u) {
    const int cur = u & 1;
    short8 afr[4], bfr[NF];
#pragma unroll
    for (int m = 0; m < 4; ++m)
      afr[m] = *(const short8*)(&As[cur][(wr * 64 + m * 16 + r16) * 32 + ((kh ^ ksw) * 8)]);
#pragma unroll
    for (int n = 0; n < NF; ++n)
      bfr[n] = *(const short8*)(&Bs[cur][(wc * HB + n * 16 + r16) * 32 + ((kh ^ ksw) * 8)]);

    if (u + 1 < NT) {
      const int ko = (u + 1) * 32;
#pragma unroll
      for (int i = 0; i < 2; ++i)
        gload_lds16(Ag + (size_t)(i * 64 + srow) * K + ko + kc * 8, &As[cur ^ 1][i * 2048 + w * 512]);
#pragma unroll
      for (int i = 0; i < BI; ++i)
        gload_lds16(Bg + (size_t)(i * 64 + srow) * K + ko + kc * 8, &Bs[cur ^ 1][i * 2048 + w * 512]);
    }

    wait_lgkm0();
    __builtin_amdgcn_s_setprio(1);
#pragma unroll
    for (int m = 0; m < 4; ++m)
#pragma unroll
      for (int n = 0; n < NF; ++n)
        acc[m][n] = __builtin_amdgcn_mfma_f32_16x16x32_bf16(afr[m], bfr[n], acc[m][n], 0, 0, 0);
    __builtin_amdgcn_s_setprio(0);

    if (u + 1 < NT) {
      wait_vmcnt<0>();                 // my stage writes visible...
      __builtin_amdgcn_s_barrier();    // ...to all waves before next reads
    }
  }

  // epilogue: D col = lane&15, row = (lane>>4)*4 + reg
  const int rowb = bm * 128 + wr * 64;
  const int colb = bn * BN + wc * HB;
#pragma unroll
  for (int m = 0; m < 4; ++m)
#pragma unroll
    for (int n = 0; n < NF; ++n)
#pragma unroll
      for (int r = 0; r < 4; ++r) {
        int row = rowb + m * 16 + kh * 4 + r;
        int col = colb + n * 16 + r16;
        float val = acc[m][n][r];
        if constexpr (sizeof(OutT) == 2) C[(size_t)row * N + col] = f2b(val);
        else                             C[(size_t)row * N + col] = val;
      }
}

// ---------- RoPE cos/sin table: tab[pos][i] for pos,i in 0..15 ----------
__global__ void rope_tab_kernel(float2* __restrict__ tab) {
  int t = threadIdx.x;   // 256 threads
  int pos = t >> 4, i = t & 15;
  float inv_freq = __expf(-(float)i * 0.5756462732485115f);  // ln(10000)/16
  float ang = (float)pos * inv_freq;
  float sn, c;
  __sincosf(ang, &sn, &c);
  tab[t] = make_float2(c, sn);
}

// ---------- RoPE(3D) + rearrange ----------
__global__ void rope_kernel(const ushort* __restrict__ qkv,
                            const float2* __restrict__ tab,
                            ushort* __restrict__ Qo, ushort* __restrict__ Ko,
                            ushort* __restrict__ Vt) {
  const int UNITS = 1344;
  int idx = blockIdx.x * 256 + threadIdx.x;
  if (idx >= 8192 * UNITS) return;
  int row = idx / UNITS;
  int unit = idx - row * UNITS;
  int bt = row >> 8, s = row & 255;
  const ushort* qr = qkv + (size_t)row * 2304;
  if (unit < 960) {
    int head, p;
    size_t srcoff;
    ushort* dst;
    if (unit < 768) {            // q
      head = unit / 48; p = unit % 48;
      srcoff = (size_t)head * 96;
      dst = Qo + ((size_t)(bt * 16 + head) * 256 + s) * 96;
    } else {                     // k
      int u = unit - 768;
      head = u / 48; p = u % 48;
      srcoff = 1536 + (size_t)head * 96;
      dst = Ko + ((size_t)(bt * 4 + head) * 256 + s) * 96;
    }
    int seg = p >> 4, i = p & 15;
    int pos = (seg == 0) ? (bt & 15) : ((seg == 1) ? (s >> 4) : (s & 15));
    float2 cs = tab[pos * 16 + i];
    float c = cs.x, sn = cs.y;
    float x1 = b2f(qr[srcoff + seg * 32 + i]);
    float x2 = b2f(qr[srcoff + seg * 32 + i + 16]);
    dst[seg * 32 + i]      = f2b(x1 * c - x2 * sn);
    dst[seg * 32 + i + 16] = f2b(x1 * sn + x2 * c);
  } else {                       // v -> transposed copy
    int u = unit - 960;
    int g = u / 96, d = u - g * 96;
    Vt[((size_t)(bt * 4 + g) * 96 + d) * 256 + s] = qr[1920 + (size_t)g * 96 + d];
  }
}

// ---------- attention v2: one block per (bt, g, qhalf); K/V staged once in LDS ----------
__global__ __launch_bounds__(512, 2) void attn2_kernel(
    const ushort* __restrict__ Q,   // [32][16][256][96]
    const ushort* __restrict__ Kr,  // [32][4][256][96]
    const ushort* __restrict__ Vt,  // [32][4][96][256]
    const int* __restrict__ mask,   // [32][256]
    ushort* __restrict__ Out) {     // [8192][1536] bf16
  __shared__ ushort Ks[256 * 104];
  __shared__ ushort Vs[96 * 264];
  __shared__ ushort Ps[8][16 * 136];
  __shared__ float Mb[256];

  const int b = blockIdx.x;
  const int qt = b & 1;
  const int g = (b >> 1) & 3;
  const int bt = b >> 3;
  const int t = threadIdx.x;
  const int l = t & 63, w = t >> 6;
  const int r16 = l & 15, kh = l >> 4;
  const int h = g * 4 + (w >> 1);
  const int qc = w & 1;

  const ushort* Kp = Kr + (size_t)(bt * 4 + g) * 256 * 96;
  const ushort* Vp = Vt + (size_t)(bt * 4 + g) * 96 * 256;

  {
    int r = t >> 1, ch = t & 1;
#pragma unroll
    for (int j = 0; j < 6; ++j)
      *(short8*)(&Ks[r * 104 + ch * 48 + j * 8]) =
          *(const short8*)(Kp + (size_t)r * 96 + ch * 48 + j * 8);
  }
#pragma unroll
  for (int i = 0; i < 6; ++i) {
    int c = t + i * 512;
    int vr = c >> 5, vc = c & 31;
    *(short8*)(&Vs[vr * 264 + vc * 8]) =
        *(const short8*)(Vp + (size_t)vr * 256 + vc * 8);
  }
  if (t < 256) Mb[t] = mask[bt * 256 + t] ? 0.0f : -1.0e9f;
  __syncthreads();

  const ushort* Qp = Q + ((size_t)(bt * 16 + h) * 256 + qt * 128 + qc * 64) * 96;
  ushort* Pw = &Ps[w][0];
  const float scale = 0.10206207261596575f;  // 1/sqrt(96)

#pragma unroll
  for (int mp = 0; mp < 2; ++mp) {
    const int qb = mp * 32;

    short8 qfA[3], qfB[3];
#pragma unroll
    for (int kc = 0; kc < 3; ++kc) {
      qfA[kc] = *(const short8*)(Qp + (size_t)(qb + r16) * 96 + kc * 32 + kh * 8);
      qfB[kc] = *(const short8*)(Qp + (size_t)(qb + 16 + r16) * 96 + kc * 32 + kh * 8);
    }

    f32x4 scA[16] = {}, scB[16] = {};
#pragma unroll
    for (int f = 0; f < 16; ++f) {
#pragma unroll
      for (int kc = 0; kc < 3; ++kc) {
        short8 kf = *(const short8*)(&Ks[(f * 16 + r16) * 104 + kc * 32 + kh * 8]);
        scA[f] = __builtin_amdgcn_mfma_f32_16x16x32_bf16(qfA[kc], kf, scA[f], 0, 0, 0);
        scB[f] = __builtin_amdgcn_mfma_f32_16x16x32_bf16(qfB[kc], kf, scB[f], 0, 0, 0);
      }
    }

#pragma unroll
    for (int f = 0; f < 16; ++f) {
      float mb = Mb[f * 16 + r16];
#pragma unroll
      for (int r = 0; r < 4; ++r) {
        scA[f][r] = scA[f][r] * scale + mb;
        scB[f][r] = scB[f][r] * scale + mb;
      }
    }

    float invA[4], invB[4];
#pragma unroll
    for (int reg = 0; reg < 4; ++reg) {
      float mxA = -3.0e38f, mxB = -3.0e38f;
#pragma unroll
      for (int f = 0; f < 16; ++f) { mxA = fmaxf(mxA, scA[f][reg]); mxB = fmaxf(mxB, scB[f][reg]); }
      for (int o = 8; o >= 1; o >>= 1) { mxA = fmaxf(mxA, __shfl_xor(mxA, o, 64)); mxB = fmaxf(mxB, __shfl_xor(mxB, o, 64)); }
      float smA = 0.f, smB = 0.f;
#pragma unroll
      for (int f = 0; f < 16; ++f) {
        float pA = __expf(scA[f][reg] - mxA);
        float pB = __expf(scB[f][reg] - mxB);
        scA[f][reg] = pA; scB[f][reg] = pB;
        smA += pA; smB += pB;
      }
      for (int o = 8; o >= 1; o >>= 1) { smA += __shfl_xor(smA, o, 64); smB += __shfl_xor(smB, o, 64); }
      invA[reg] = 1.0f / smA;
      invB[reg] = 1.0f / smB;
    }

    short8 pfA[8], pfB[8];
#pragma unroll
    for (int ck = 0; ck < 2; ++ck) {
#pragma unroll
      for (int f = 0; f < 8; ++f)
#pragma unroll
        for (int reg = 0; reg < 4; ++reg)
          Pw[(kh * 4 + reg) * 136 + f * 16 + r16] = f2b(scA[ck * 8 + f][reg]);
#pragma unroll
      for (int kc = 0; kc < 4; ++kc)
        pfA[ck * 4 + kc] = *(const short8*)(&Pw[r16 * 136 + kc * 32 + kh * 8]);
    }
#pragma unroll
    for (int ck = 0; ck < 2; ++ck) {
#pragma unroll
      for (int f = 0; f < 8; ++f)
#pragma unroll
        for (int reg = 0; reg < 4; ++reg)
          Pw[(kh * 4 + reg) * 136 + f * 16 + r16] = f2b(scB[ck * 8 + f][reg]);
#pragma unroll
      for (int kc = 0; kc < 4; ++kc)
        pfB[ck * 4 + kc] = *(const short8*)(&Pw[r16 * 136 + kc * 32 + kh * 8]);
    }

    f32x4 oA[6] = {}, oB[6] = {};
#pragma unroll
    for (int dt = 0; dt < 6; ++dt) {
#pragma unroll
      for (int kc = 0; kc < 8; ++kc) {
        short8 vf = *(const short8*)(&Vs[(dt * 16 + r16) * 264 + kc * 32 + kh * 8]);
        oA[dt] = __builtin_amdgcn_mfma_f32_16x16x32_bf16(pfA[kc], vf, oA[dt], 0, 0, 0);
        oB[dt] = __builtin_amdgcn_mfma_f32_16x16x32_bf16(pfB[kc], vf, oB[dt], 0, 0, 0);
      }
    }

    const int rbase = bt * 256 + qt * 128 + qc * 64 + qb;
#pragma unroll
    for (int dt = 0; dt < 6; ++dt)
#pragma unroll
      for (int reg = 0; reg < 4; ++reg) {
        int col = h * 96 + dt * 16 + r16;
        Out[(size_t)(rbase + kh * 4 + reg) * 1536 + col]      = f2b(oA[dt][reg] * invA[reg]);
        Out[(size_t)(rbase + 16 + kh * 4 + reg) * 1536 + col] = f2b(oB[dt][reg] * invB[reg]);
      }
  }
}

// ---------- launch ----------
extern "C" void kernel_launch(void* const* d_in, const int* in_sizes, int n_in,
                              void* d_out, int out_size, void* d_ws, size_t ws_size,
                              hipStream_t stream) {
  const float* x     = (const float*)d_in[0];   // [2][16][256][1536]
  const int* pmask   = (const int*)d_in[1];     // [32][256]
  const float* w_qkv = (const float*)d_in[2];   // [2304][1536]
  const float* w_o   = (const float*)d_in[3];   // [1536][1536]
  float* out = (float*)d_out;                   // [8192][1536] f32

  char* ws = (char*)d_ws;
  ushort* Xb  = (ushort*)(ws + 0);          // 8192x1536 bf16
  ushort* Wq  = (ushort*)(ws + 25165824);   // 2304x1536 bf16
  ushort* Wo  = (ushort*)(ws + 32243712);   // 1536x1536 bf16
  ushort* QKV = (ushort*)(ws + 36962304);   // 8192x2304 bf16
  ushort* Qr  = (ushort*)(ws + 74711040);   // 32x16x256x96
  ushort* Kr  = (ushort*)(ws + 99876864);   // 32x4x256x96
  ushort* Vt  = (ushort*)(ws + 106168320);  // 32x4x96x256
  float2* Tab = (float2*)(ws + 112459776);  // 256 x float2 rope table
  ushort* Attn = Xb;                        // reuse Xb slot after gemm1

  cvt_kernel<<<3145728 / 256, 256, 0, stream>>>(x, Xb, 3145728);
  cvt_kernel<<<884736 / 256, 256, 0, stream>>>(w_qkv, Wq, 884736);
  cvt_kernel<<<589824 / 256, 256, 0, stream>>>(w_o, Wo, 589824);
  rope_tab_kernel<<<1, 256, 0, stream>>>(Tab);

  gemm4<192, ushort><<<768, 256, 0, stream>>>(Xb, Wq, QKV, 2304, 1536);

  rope_kernel<<<(8192 * 1344) / 256, 256, 0, stream>>>(QKV, Tab, Qr, Kr, Vt);

  attn2_kernel<<<256, 512, 0, stream>>>(Qr, Kr, Vt, pmask, Attn);

  gemm4<128, float><<<768, 256, 0, stream>>>(Attn, Wo, out, 1536, 1536);
}

// Round 6
// 181.623 us; speedup vs baseline: 1.0534x; 1.0534x over previous
//
#include <hip/hip_runtime.h>
#include <hip/hip_bf16.h>
#include <stdint.h>

// ---------- common types / helpers ----------
typedef __attribute__((ext_vector_type(8))) short short8;   // 8 bf16 = 4 VGPR (MFMA A/B frag)
typedef __attribute__((ext_vector_type(4))) float f32x4;    // MFMA C/D frag
typedef __attribute__((ext_vector_type(4))) float f4;
typedef __attribute__((ext_vector_type(4))) short s4;

typedef __attribute__((address_space(1))) const void gvoid_t;
typedef __attribute__((address_space(3))) void lvoid_t;

__device__ __forceinline__ void gload_lds16(const void* g, void* l) {
  __builtin_amdgcn_global_load_lds((gvoid_t*)g, (lvoid_t*)l, 16, 0, 0);
}

__device__ __forceinline__ ushort f2b(float f) {  // f32 -> bf16 RNE
  union { float f; uint32_t u; } v; v.f = f;
  return (ushort)((v.u + 0x7fffu + ((v.u >> 16) & 1u)) >> 16);
}
__device__ __forceinline__ float b2f(ushort b) {
  union { uint32_t u; float f; } v; v.u = ((uint32_t)b) << 16;
  return v.f;
}

template <int N> __device__ __forceinline__ void wait_vmcnt();
template <> __device__ __forceinline__ void wait_vmcnt<0>() { asm volatile("s_waitcnt vmcnt(0)" ::: "memory"); }
template <> __device__ __forceinline__ void wait_vmcnt<1>() { asm volatile("s_waitcnt vmcnt(1)" ::: "memory"); }
template <> __device__ __forceinline__ void wait_vmcnt<2>() { asm volatile("s_waitcnt vmcnt(2)" ::: "memory"); }
template <> __device__ __forceinline__ void wait_vmcnt<3>() { asm volatile("s_waitcnt vmcnt(3)" ::: "memory"); }

__device__ __forceinline__ void wait_lgkm0() {
  asm volatile("s_waitcnt lgkmcnt(0)" ::: "memory");
  __builtin_amdgcn_sched_barrier(0);   // rule #18: keep MFMA below the wait
}

// Stage ROWS rows (row stride = 64 bf16 in LDS, linear) from global (leading dim ldg).
// Pre-swizzled source: LDS[row][c] gets Global[row][c ^ (row&7)] (c = 16B chunk).
template <int ROWS>
__device__ __forceinline__ void stage_rows(const ushort* __restrict__ g, int ldg,
                                           ushort* lds, int w, int l, int sc) {
#pragma unroll
  for (int i = 0; i < ROWS / 64; ++i)
    gload_lds16(g + (size_t)(i * 64 + w * 8 + (l >> 3)) * ldg + sc * 8,
                lds + i * 4096 + w * 512);
  if constexpr ((ROWS % 64) != 0) {
    if (w < (ROWS % 64) / 8)
      gload_lds16(g + (size_t)((ROWS / 64) * 64 + w * 8 + (l >> 3)) * ldg + sc * 8,
                  lds + (ROWS / 64) * 4096 + w * 512);
  }
}

// ---------- f32 -> bf16 cast kernel ----------
__global__ void cvt_kernel(const float* __restrict__ in, ushort* __restrict__ out, int n4) {
  int i = blockIdx.x * 256 + threadIdx.x;
  if (i < n4) {
    f4 v = ((const f4*)in)[i];
    s4 o;
    o.x = (short)f2b(v.x); o.y = (short)f2b(v.y);
    o.z = (short)f2b(v.z); o.w = (short)f2b(v.w);
    ((s4*)out)[i] = o;
  }
}

// ---------- bf16 GEMM v5: 4-phase fine-interleave, counted vmcnt ----------
// C[M,N] = A[M,K] @ B[N,K]^T. BM=256, BN in {288,192}; grid = 32bm x 8bn = 256
// (tail-free, 1/CU). XCD-owned bm chunks. 8 waves 4Mx2N (wave 64 x BN/2).
// Per K-tile: 4 phases {ds_read subtile ∥ stage unit -> bar -> lgkm0 -> MFMA
// cluster -> bar}; single counted vmcnt at ph3 leaves B0(u+2) in flight.
template <int BN, typename OutT>
__global__ __launch_bounds__(512, 2) void gemm5(const ushort* __restrict__ A,
                                                const ushort* __restrict__ B,
                                                OutT* __restrict__ C,
                                                int N, int K) {
  constexpr int NF = BN / 32;            // 9 | 6 n-frags per wave
  constexpr int NH0 = (NF + 1) / 2;      // 5 | 3
  constexpr int NH1 = NF - NH0;          // 4 | 3
  constexpr int RB = BN / 2;             // 144 | 96  (B half-tile rows)
  constexpr int BF = RB / 64;            // full stage rounds per B half: 2 | 1
  constexpr int BE = (RB % 64) / 8;      // waves w<BE issue one extra:  2 | 4

  __shared__ ushort As[2][256 * 64];
  __shared__ ushort Bs[2][BN * 64];

  const int tid = threadIdx.x;
  const int l = tid & 63, w = tid >> 6;
  const int wr = w >> 1, wc = w & 1;     // 4M x 2N
  const int r16 = l & 15, kh = l >> 4;
  const int sc = (l & 7) ^ (l >> 3);     // pre-swizzled source chunk

  const int xcd = blockIdx.x & 7;
  const int ii = blockIdx.x >> 3;        // 0..31
  const int bm = xcd * 4 + (ii & 3);     // XCD owns 4 contiguous A panels
  const int bn = ii >> 2;                // 0..7
  const ushort* Ag = A + (size_t)bm * 256 * K;
  const ushort* Bg = B + (size_t)bn * BN * K;
  const int NT = K >> 6;

  // prologue: A(0), B0(0), B1(0) -> buf0 ; B0(1) -> buf1 (left in flight)
  stage_rows<256>(Ag,                   K, &As[0][0],       w, l, sc);
  stage_rows<RB >(Bg,                   K, &Bs[0][0],       w, l, sc);
  stage_rows<RB >(Bg + (size_t)RB * K,  K, &Bs[0][RB * 64], w, l, sc);
  stage_rows<RB >(Bg + 64,              K, &Bs[1][0],       w, l, sc);
  if (w < BE) wait_vmcnt<BF + 1>(); else wait_vmcnt<BF>();
  __builtin_amdgcn_s_barrier();

  f32x4 acc[4][NF] = {};
  short8 afr[2][2], bfr[NH0][2];

  for (int u = 0; u < NT; ++u) {
    const int cur = u & 1;
    const ushort* Asb = &As[cur][0];
    const ushort* Bsb = &Bs[cur][0];
    ushort* Asn = &As[cur ^ 1][0];
    ushort* Bsn = &Bs[cur ^ 1][0];
    const int kt1 = (u + 1) << 6, kt2 = (u + 2) << 6;
    const bool st1 = (u + 1 < NT), st2 = (u + 2 < NT);

    // ===== phase 0: read B(nh0) + A(m0,m1); stage A(u+1); MFMA m01 x nh0
#pragma unroll
    for (int n = 0; n < NH0; ++n)
#pragma unroll
      for (int ks = 0; ks < 2; ++ks)
        bfr[n][ks] = *(const short8*)(Bsb + (wc * RB + n * 16 + r16) * 64 +
                                      (((ks * 4 + kh) ^ (r16 & 7)) * 8));
#pragma unroll
    for (int mm = 0; mm < 2; ++mm)
#pragma unroll
      for (int ks = 0; ks < 2; ++ks)
        afr[mm][ks] = *(const short8*)(Asb + (wr * 64 + mm * 16 + r16) * 64 +
                                       (((ks * 4 + kh) ^ (r16 & 7)) * 8));
    if (st1) stage_rows<256>(Ag + kt1, K, Asn, w, l, sc);
    __builtin_amdgcn_s_barrier();
    wait_lgkm0();
    __builtin_amdgcn_s_setprio(1);
#pragma unroll
    for (int mm = 0; mm < 2; ++mm)
#pragma unroll
      for (int n = 0; n < NH0; ++n)
#pragma unroll
        for (int ks = 0; ks < 2; ++ks)
          acc[mm][n] = __builtin_amdgcn_mfma_f32_16x16x32_bf16(afr[mm][ks], bfr[n][ks], acc[mm][n], 0, 0, 0);
    __builtin_amdgcn_s_setprio(0);
    __builtin_amdgcn_s_barrier();

    // ===== phase 1: read A(m2,m3); stage B1(u+1); MFMA m23 x nh0
#pragma unroll
    for (int mm = 0; mm < 2; ++mm)
#pragma unroll
      for (int ks = 0; ks < 2; ++ks)
        afr[mm][ks] = *(const short8*)(Asb + (wr * 64 + (2 + mm) * 16 + r16) * 64 +
                                       (((ks * 4 + kh) ^ (r16 & 7)) * 8));
    if (st1) stage_rows<RB>(Bg + (size_t)RB * K + kt1, K, Bsn + RB * 64, w, l, sc);
    __builtin_amdgcn_s_barrier();
    wait_lgkm0();
    __builtin_amdgcn_s_setprio(1);
#pragma unroll
    for (int mm = 0; mm < 2; ++mm)
#pragma unroll
      for (int n = 0; n < NH0; ++n)
#pragma unroll
        for (int ks = 0; ks < 2; ++ks)
          acc[2 + mm][n] = __builtin_amdgcn_mfma_f32_16x16x32_bf16(afr[mm][ks], bfr[n][ks], acc[2 + mm][n], 0, 0, 0);
    __builtin_amdgcn_s_setprio(0);
    __builtin_amdgcn_s_barrier();

    // ===== phase 2: read B(nh1); MFMA m23 x nh1 (afr still holds m2,m3)
#pragma unroll
    for (int n = 0; n < NH1; ++n)
#pragma unroll
      for (int ks = 0; ks < 2; ++ks)
        bfr[n][ks] = *(const short8*)(Bsb + (wc * RB + (NH0 + n) * 16 + r16) * 64 +
                                      (((ks * 4 + kh) ^ (r16 & 7)) * 8));
    __builtin_amdgcn_s_barrier();
    wait_lgkm0();
    __builtin_amdgcn_s_setprio(1);
#pragma unroll
    for (int mm = 0; mm < 2; ++mm)
#pragma unroll
      for (int n = 0; n < NH1; ++n)
#pragma unroll
        for (int ks = 0; ks < 2; ++ks)
          acc[2 + mm][NH0 + n] = __builtin_amdgcn_mfma_f32_16x16x32_bf16(afr[mm][ks], bfr[n][ks], acc[2 + mm][NH0 + n], 0, 0, 0);
    __builtin_amdgcn_s_setprio(0);
    __builtin_amdgcn_s_barrier();

    // ===== phase 3: re-read A(m0,m1); stage B0(u+2) into buf[cur]; counted vmcnt
#pragma unroll
    for (int mm = 0; mm < 2; ++mm)
#pragma unroll
      for (int ks = 0; ks < 2; ++ks)
        afr[mm][ks] = *(const short8*)(Asb + (wr * 64 + mm * 16 + r16) * 64 +
                                       (((ks * 4 + kh) ^ (r16 & 7)) * 8));
    if (st2) stage_rows<RB>(Bg + kt2, K, &Bs[cur][0], w, l, sc);
    // beta wait: drain everything except B0(u+2)'s own-wave loads
    if (st2) { if (w < BE) wait_vmcnt<BF + 1>(); else wait_vmcnt<BF>(); }
    else wait_vmcnt<0>();
    __builtin_amdgcn_s_barrier();
    wait_lgkm0();
    __builtin_amdgcn_s_setprio(1);
#pragma unroll
    for (int mm = 0; mm < 2; ++mm)
#pragma unroll
      for (int n = 0; n < NH1; ++n)
#pragma unroll
        for (int ks = 0; ks < 2; ++ks)
          acc[mm][NH0 + n] = __builtin_amdgcn_mfma_f32_16x16x32_bf16(afr[mm][ks], bfr[n][ks], acc[mm][NH0 + n], 0, 0, 0);
    __builtin_amdgcn_s_setprio(0);
    __builtin_amdgcn_s_barrier();
  }

  // epilogue: D col = lane&15, row = (lane>>4)*4 + reg
  const int rowb = bm * 256 + wr * 64;
  const int colb = bn * BN + wc * RB;
#pragma unroll
  for (int m = 0; m < 4; ++m)
#pragma unroll
    for (int n = 0; n < NF; ++n)
#pragma unroll
      for (int r = 0; r < 4; ++r) {
        int row = rowb + m * 16 + kh * 4 + r;
        int col = colb + n * 16 + r16;
        float val = acc[m][n][r];
        if constexpr (sizeof(OutT) == 2) C[(size_t)row * N + col] = f2b(val);
        else                             C[(size_t)row * N + col] = val;
      }
}

// ---------- RoPE cos/sin table: tab[pos][i] for pos,i in 0..15 ----------
__global__ void rope_tab_kernel(float2* __restrict__ tab) {
  int t = threadIdx.x;   // 256 threads
  int pos = t >> 4, i = t & 15;
  float inv_freq = __expf(-(float)i * 0.5756462732485115f);  // ln(10000)/16
  float ang = (float)pos * inv_freq;
  float sn, c;
  __sincosf(ang, &sn, &c);
  tab[t] = make_float2(c, sn);
}

// ---------- RoPE(3D) + rearrange ----------
__global__ void rope_kernel(const ushort* __restrict__ qkv,
                            const float2* __restrict__ tab,
                            ushort* __restrict__ Qo, ushort* __restrict__ Ko,
                            ushort* __restrict__ Vt) {
  const int UNITS = 1344;
  int idx = blockIdx.x * 256 + threadIdx.x;
  if (idx >= 8192 * UNITS) return;
  int row = idx / UNITS;
  int unit = idx - row * UNITS;
  int bt = row >> 8, s = row & 255;
  const ushort* qr = qkv + (size_t)row * 2304;
  if (unit < 960) {
    int head, p;
    size_t srcoff;
    ushort* dst;
    if (unit < 768) {            // q
      head = unit / 48; p = unit % 48;
      srcoff = (size_t)head * 96;
      dst = Qo + ((size_t)(bt * 16 + head) * 256 + s) * 96;
    } else {                     // k
      int u = unit - 768;
      head = u / 48; p = u % 48;
      srcoff = 1536 + (size_t)head * 96;
      dst = Ko + ((size_t)(bt * 4 + head) * 256 + s) * 96;
    }
    int seg = p >> 4, i = p & 15;
    int pos = (seg == 0) ? (bt & 15) : ((seg == 1) ? (s >> 4) : (s & 15));
    float2 cs = tab[pos * 16 + i];
    float c = cs.x, sn = cs.y;
    float x1 = b2f(qr[srcoff + seg * 32 + i]);
    float x2 = b2f(qr[srcoff + seg * 32 + i + 16]);
    dst[seg * 32 + i]      = f2b(x1 * c - x2 * sn);
    dst[seg * 32 + i + 16] = f2b(x1 * sn + x2 * c);
  } else {                       // v -> transposed copy
    int u = unit - 960;
    int g = u / 96, d = u - g * 96;
    Vt[((size_t)(bt * 4 + g) * 96 + d) * 256 + s] = qr[1920 + (size_t)g * 96 + d];
  }
}

// ---------- attention v2: one block per (bt, g, qhalf); K/V staged once in LDS ----------
__global__ __launch_bounds__(512, 2) void attn2_kernel(
    const ushort* __restrict__ Q,   // [32][16][256][96]
    const ushort* __restrict__ Kr,  // [32][4][256][96]
    const ushort* __restrict__ Vt,  // [32][4][96][256]
    const int* __restrict__ mask,   // [32][256]
    ushort* __restrict__ Out) {     // [8192][1536] bf16
  __shared__ ushort Ks[256 * 104];
  __shared__ ushort Vs[96 * 264];
  __shared__ ushort Ps[8][16 * 136];
  __shared__ float Mb[256];

  const int b = blockIdx.x;
  const int qt = b & 1;
  const int g = (b >> 1) & 3;
  const int bt = b >> 3;
  const int t = threadIdx.x;
  const int l = t & 63, w = t >> 6;
  const int r16 = l & 15, kh = l >> 4;
  const int h = g * 4 + (w >> 1);
  const int qc = w & 1;

  const ushort* Kp = Kr + (size_t)(bt * 4 + g) * 256 * 96;
  const ushort* Vp = Vt + (size_t)(bt * 4 + g) * 96 * 256;

  {
    int r = t >> 1, ch = t & 1;
#pragma unroll
    for (int j = 0; j < 6; ++j)
      *(short8*)(&Ks[r * 104 + ch * 48 + j * 8]) =
          *(const short8*)(Kp + (size_t)r * 96 + ch * 48 + j * 8);
  }
#pragma unroll
  for (int i = 0; i < 6; ++i) {
    int c = t + i * 512;
    int vr = c >> 5, vc = c & 31;
    *(short8*)(&Vs[vr * 264 + vc * 8]) =
        *(const short8*)(Vp + (size_t)vr * 256 + vc * 8);
  }
  if (t < 256) Mb[t] = mask[bt * 256 + t] ? 0.0f : -1.0e9f;
  __syncthreads();

  const ushort* Qp = Q + ((size_t)(bt * 16 + h) * 256 + qt * 128 + qc * 64) * 96;
  ushort* Pw = &Ps[w][0];
  const float scale = 0.10206207261596575f;  // 1/sqrt(96)

#pragma unroll
  for (int mp = 0; mp < 2; ++mp) {
    const int qb = mp * 32;

    short8 qfA[3], qfB[3];
#pragma unroll
    for (int kc = 0; kc < 3; ++kc) {
      qfA[kc] = *(const short8*)(Qp + (size_t)(qb + r16) * 96 + kc * 32 + kh * 8);
      qfB[kc] = *(const short8*)(Qp + (size_t)(qb + 16 + r16) * 96 + kc * 32 + kh * 8);
    }

    f32x4 scA[16] = {}, scB[16] = {};
#pragma unroll
    for (int f = 0; f < 16; ++f) {
#pragma unroll
      for (int kc = 0; kc < 3; ++kc) {
        short8 kf = *(const short8*)(&Ks[(f * 16 + r16) * 104 + kc * 32 + kh * 8]);
        scA[f] = __builtin_amdgcn_mfma_f32_16x16x32_bf16(qfA[kc], kf, scA[f], 0, 0, 0);
        scB[f] = __builtin_amdgcn_mfma_f32_16x16x32_bf16(qfB[kc], kf, scB[f], 0, 0, 0);
      }
    }

#pragma unroll
    for (int f = 0; f < 16; ++f) {
      float mb = Mb[f * 16 + r16];
#pragma unroll
      for (int r = 0; r < 4; ++r) {
        scA[f][r] = scA[f][r] * scale + mb;
        scB[f][r] = scB[f][r] * scale + mb;
      }
    }

    float invA[4], invB[4];
#pragma unroll
    for (int reg = 0; reg < 4; ++reg) {
      float mxA = -3.0e38f, mxB = -3.0e38f;
#pragma unroll
      for (int f = 0; f < 16; ++f) { mxA = fmaxf(mxA, scA[f][reg]); mxB = fmaxf(mxB, scB[f][reg]); }
      for (int o = 8; o >= 1; o >>= 1) { mxA = fmaxf(mxA, __shfl_xor(mxA, o, 64)); mxB = fmaxf(mxB, __shfl_xor(mxB, o, 64)); }
      float smA = 0.f, smB = 0.f;
#pragma unroll
      for (int f = 0; f < 16; ++f) {
        float pA = __expf(scA[f][reg] - mxA);
        float pB = __expf(scB[f][reg] - mxB);
        scA[f][reg] = pA; scB[f][reg] = pB;
        smA += pA; smB += pB;
      }
      for (int o = 8; o >= 1; o >>= 1) { smA += __shfl_xor(smA, o, 64); smB += __shfl_xor(smB, o, 64); }
      invA[reg] = 1.0f / smA;
      invB[reg] = 1.0f / smB;
    }

    short8 pfA[8], pfB[8];
#pragma unroll
    for (int ck = 0; ck < 2; ++ck) {
#pragma unroll
      for (int f = 0; f < 8; ++f)
#pragma unroll
        for (int reg = 0; reg < 4; ++reg)
          Pw[(kh * 4 + reg) * 136 + f * 16 + r16] = f2b(scA[ck * 8 + f][reg]);
#pragma unroll
      for (int kc = 0; kc < 4; ++kc)
        pfA[ck * 4 + kc] = *(const short8*)(&Pw[r16 * 136 + kc * 32 + kh * 8]);
    }
#pragma unroll
    for (int ck = 0; ck < 2; ++ck) {
#pragma unroll
      for (int f = 0; f < 8; ++f)
#pragma unroll
        for (int reg = 0; reg < 4; ++reg)
          Pw[(kh * 4 + reg) * 136 + f * 16 + r16] = f2b(scB[ck * 8 + f][reg]);
#pragma unroll
      for (int kc = 0; kc < 4; ++kc)
        pfB[ck * 4 + kc] = *(const short8*)(&Pw[r16 * 136 + kc * 32 + kh * 8]);
    }

    f32x4 oA[6] = {}, oB[6] = {};
#pragma unroll
    for (int dt = 0; dt < 6; ++dt) {
#pragma unroll
      for (int kc = 0; kc < 8; ++kc) {
        short8 vf = *(const short8*)(&Vs[(dt * 16 + r16) * 264 + kc * 32 + kh * 8]);
        oA[dt] = __builtin_amdgcn_mfma_f32_16x16x32_bf16(pfA[kc], vf, oA[dt], 0, 0, 0);
        oB[dt] = __builtin_amdgcn_mfma_f32_16x16x32_bf16(pfB[kc], vf, oB[dt], 0, 0, 0);
      }
    }

    const int rbase = bt * 256 + qt * 128 + qc * 64 + qb;
#pragma unroll
    for (int dt = 0; dt < 6; ++dt)
#pragma unroll
      for (int reg = 0; reg < 4; ++reg) {
        int col = h * 96 + dt * 16 + r16;
        Out[(size_t)(rbase + kh * 4 + reg) * 1536 + col]      = f2b(oA[dt][reg] * invA[reg]);
        Out[(size_t)(rbase + 16 + kh * 4 + reg) * 1536 + col] = f2b(oB[dt][reg] * invB[reg]);
      }
  }
}

// ---------- launch ----------
extern "C" void kernel_launch(void* const* d_in, const int* in_sizes, int n_in,
                              void* d_out, int out_size, void* d_ws, size_t ws_size,
                              hipStream_t stream) {
  const float* x     = (const float*)d_in[0];   // [2][16][256][1536]
  const int* pmask   = (const int*)d_in[1];     // [32][256]
  const float* w_qkv = (const float*)d_in[2];   // [2304][1536]
  const float* w_o   = (const float*)d_in[3];   // [1536][1536]
  float* out = (float*)d_out;                   // [8192][1536] f32

  char* ws = (char*)d_ws;
  ushort* Xb  = (ushort*)(ws + 0);          // 8192x1536 bf16
  ushort* Wq  = (ushort*)(ws + 25165824);   // 2304x1536 bf16
  ushort* Wo  = (ushort*)(ws + 32243712);   // 1536x1536 bf16
  ushort* QKV = (ushort*)(ws + 36962304);   // 8192x2304 bf16
  ushort* Qr  = (ushort*)(ws + 74711040);   // 32x16x256x96
  ushort* Kr  = (ushort*)(ws + 99876864);   // 32x4x256x96
  ushort* Vt  = (ushort*)(ws + 106168320);  // 32x4x96x256
  float2* Tab = (float2*)(ws + 112459776);  // 256 x float2 rope table
  ushort* Attn = Xb;                        // reuse Xb slot after gemm1

  cvt_kernel<<<3145728 / 256, 256, 0, stream>>>(x, Xb, 3145728);
  cvt_kernel<<<884736 / 256, 256, 0, stream>>>(w_qkv, Wq, 884736);
  cvt_kernel<<<589824 / 256, 256, 0, stream>>>(w_o, Wo, 589824);
  rope_tab_kernel<<<1, 256, 0, stream>>>(Tab);

  gemm5<288, ushort><<<256, 512, 0, stream>>>(Xb, Wq, QKV, 2304, 1536);

  rope_kernel<<<(8192 * 1344) / 256, 256, 0, stream>>>(QKV, Tab, Qr, Kr, Vt);

  attn2_kernel<<<256, 512, 0, stream>>>(Qr, Kr, Vt, pmask, Attn);

  gemm5<192, float><<<256, 512, 0, stream>>>(Attn, Wo, out, 1536, 1536);
}

// Round 7
// 168.228 us; speedup vs baseline: 1.1373x; 1.0796x over previous
//
#include <hip/hip_runtime.h>
#include <hip/hip_bf16.h>
#include <stdint.h>

// ---------- common types / helpers ----------
typedef __attribute__((ext_vector_type(8))) short short8;   // 8 bf16 = 4 VGPR (MFMA A/B frag)
typedef __attribute__((ext_vector_type(4))) float f32x4;    // MFMA C/D frag
typedef __attribute__((ext_vector_type(4))) float f4;
typedef __attribute__((ext_vector_type(4))) short s4;

typedef __attribute__((address_space(1))) const void gvoid_t;
typedef __attribute__((address_space(3))) void lvoid_t;

__device__ __forceinline__ void gload_lds16(const void* g, void* l) {
  __builtin_amdgcn_global_load_lds((gvoid_t*)g, (lvoid_t*)l, 16, 0, 0);
}

__device__ __forceinline__ ushort f2b(float f) {  // f32 -> bf16 RNE
  union { float f; uint32_t u; } v; v.f = f;
  return (ushort)((v.u + 0x7fffu + ((v.u >> 16) & 1u)) >> 16);
}
__device__ __forceinline__ float b2f(ushort b) {
  union { uint32_t u; float f; } v; v.u = ((uint32_t)b) << 16;
  return v.f;
}

template <int N> __device__ __forceinline__ void wait_vmcnt();
template <> __device__ __forceinline__ void wait_vmcnt<0>() { asm volatile("s_waitcnt vmcnt(0)" ::: "memory"); }

__device__ __forceinline__ void wait_lgkm0() {
  asm volatile("s_waitcnt lgkmcnt(0)" ::: "memory");
  __builtin_amdgcn_sched_barrier(0);   // rule #18: keep MFMA below the wait
}

// ---------- f32 -> bf16 cast kernel ----------
__global__ void cvt_kernel(const float* __restrict__ in, ushort* __restrict__ out, int n4) {
  int i = blockIdx.x * 256 + threadIdx.x;
  if (i < n4) {
    f4 v = ((const f4*)in)[i];
    s4 o;
    o.x = (short)f2b(v.x); o.y = (short)f2b(v.y);
    o.z = (short)f2b(v.z); o.w = (short)f2b(v.w);
    ((s4*)out)[i] = o;
  }
}

// ---------- bf16 GEMM v6: minimal-barrier, XOR-folded addressing ----------
// C[M,N] = A[M,K] @ B[N,K]^T. BM=256, BN in {288,192}; grid = 32bm x 8bn = 256
// (tail-free, 1/CU), XCD-owned bm chunks. 8 waves 4Mx2N (wave 64 x BN/2).
// Per K-tile: 2 ks-phases {13 ds_read (1-XOR addressing) ; stage unit ;
// lgkm0 ; 4*NF MFMA} + ONE boundary vmcnt(0)+barrier. Reads = minimal 26/tile.
// LDS read addr = row*128 + ((ks*4+kh)^(r16&7))*16  ==  PA ^ (ks*64) + m*2048,
// PA = row0*128 + (kh*16 ^ (r16&7)*16)  (shift distributes over XOR; k-chunk
// bits 4-6 disjoint from row bits >=7).
template <int BN, typename OutT>
__global__ __launch_bounds__(512, 2) void gemm6(const ushort* __restrict__ A,
                                                const ushort* __restrict__ B,
                                                OutT* __restrict__ C,
                                                int N, int K) {
  constexpr int NF = BN / 32;            // 9 | 6 n-frags per wave
  constexpr int RB = BN / 2;             // 144 | 96
  constexpr int ABUF = 256 * 64;         // ushorts per A buffer
  constexpr int BBUF = BN * 64;
  constexpr uint ABYTE = ABUF * 2;       // 32768
  constexpr uint BBYTE = BBUF * 2;       // 36864 | 24576
  constexpr int BRND = BN / 64;          // full 64-row B stage rounds: 4 | 3
  constexpr int BTW = (BN % 64) / 8;     // tail waves: 4 | 0

  __shared__ ushort As[2 * ABUF];
  __shared__ ushort Bs[2 * BBUF];

  const int tid = threadIdx.x;
  const int l = tid & 63, w = tid >> 6;
  const int wr = w >> 1, wc = w & 1;     // 4M x 2N
  const int r16 = l & 15, kh = l >> 4;
  const int sc = (l & 7) ^ (l >> 3);     // pre-swizzled stage source chunk
  const int srow = w * 8 + (l >> 3);     // stage row within a 64-row round

  const int xcd = blockIdx.x & 7;
  const int ii = blockIdx.x >> 3;        // 0..31
  const int bm = xcd * 4 + (ii & 3);     // XCD owns 4 contiguous A panels
  const int bn = ii >> 2;                // 0..7
  const ushort* Ag = A + (size_t)bm * 256 * K;
  const ushort* Bg = B + (size_t)bn * BN * K;
  const int NT = K >> 6;

  const char* AsR = (const char*)As;
  const char* BsR = (const char*)Bs;
  const uint khsw = ((uint)kh * 16) ^ ((uint)(r16 & 7) * 16);
  const uint PA = (uint)(wr * 64 + r16) * 128 + khsw;
  const uint PB = (uint)(wc * RB + r16) * 128 + khsw;

  // persistent stage pointers (advance +64 per K-tile)
  const ushort* ga[4];
  const ushort* gb[BRND];
  const ushort* gbt = nullptr;
#pragma unroll
  for (int i = 0; i < 4; ++i) ga[i] = Ag + (size_t)(i * 64 + srow) * K + sc * 8;
#pragma unroll
  for (int i = 0; i < BRND; ++i) gb[i] = Bg + (size_t)(i * 64 + srow) * K + sc * 8;
  if constexpr (BTW > 0) gbt = Bg + (size_t)(BRND * 64 + srow) * K + sc * 8;

  // prologue: stage tile 0 into buf0
#pragma unroll
  for (int i = 0; i < 4; ++i) gload_lds16(ga[i], As + i * 4096 + w * 512);
#pragma unroll
  for (int i = 0; i < BRND; ++i) gload_lds16(gb[i], Bs + i * 4096 + w * 512);
  if constexpr (BTW > 0) { if (w < BTW) gload_lds16(gbt, Bs + BRND * 4096 + w * 512); }
#pragma unroll
  for (int i = 0; i < 4; ++i) ga[i] += 64;
#pragma unroll
  for (int i = 0; i < BRND; ++i) gb[i] += 64;
  if constexpr (BTW > 0) gbt += 64;
  wait_vmcnt<0>();
  __builtin_amdgcn_s_barrier();

  f32x4 acc[4][NF] = {};
  short8 afr[4], bfr[NF];

  for (int u = 0; u < NT; ++u) {
    const int cur = u & 1;
    const uint aoff = cur ? ABYTE : 0u;
    const uint boff = cur ? BBYTE : 0u;
    ushort* An = As + (cur ^ 1) * ABUF;
    ushort* Bn = Bs + (cur ^ 1) * BBUF;
    const bool st = (u + 1 < NT);

    // ===== phase 0 (ks = 0): reads + stage A(u+1) + MFMA all-m x all-n
    {
      const uint pa = PA + aoff, pb = PB + boff;
#pragma unroll
      for (int m = 0; m < 4; ++m)
        afr[m] = *(const short8*)(AsR + pa + m * 2048);
#pragma unroll
      for (int n = 0; n < NF; ++n)
        bfr[n] = *(const short8*)(BsR + pb + n * 2048);
    }
    if (st) {
#pragma unroll
      for (int i = 0; i < 4; ++i) gload_lds16(ga[i], An + i * 4096 + w * 512);
    }
    wait_lgkm0();
    __builtin_amdgcn_s_setprio(1);
#pragma unroll
    for (int m = 0; m < 4; ++m)
#pragma unroll
      for (int n = 0; n < NF; ++n)
        acc[m][n] = __builtin_amdgcn_mfma_f32_16x16x32_bf16(afr[m], bfr[n], acc[m][n], 0, 0, 0);
    __builtin_amdgcn_s_setprio(0);

    // ===== phase 1 (ks = 1): reads (XOR 64) + stage B(u+1) + MFMA
    {
      const uint pa = (PA ^ 64u) + aoff, pb = (PB ^ 64u) + boff;
#pragma unroll
      for (int m = 0; m < 4; ++m)
        afr[m] = *(const short8*)(AsR + pa + m * 2048);
#pragma unroll
      for (int n = 0; n < NF; ++n)
        bfr[n] = *(const short8*)(BsR + pb + n * 2048);
    }
    if (st) {
#pragma unroll
      for (int i = 0; i < BRND; ++i) gload_lds16(gb[i], Bn + i * 4096 + w * 512);
      if constexpr (BTW > 0) { if (w < BTW) gload_lds16(gbt, Bn + BRND * 4096 + w * 512); }
    }
    wait_lgkm0();
    __builtin_amdgcn_s_setprio(1);
#pragma unroll
    for (int m = 0; m < 4; ++m)
#pragma unroll
      for (int n = 0; n < NF; ++n)
        acc[m][n] = __builtin_amdgcn_mfma_f32_16x16x32_bf16(afr[m], bfr[n], acc[m][n], 0, 0, 0);
    __builtin_amdgcn_s_setprio(0);

    // ===== boundary: advance pointers; drain; sync
#pragma unroll
    for (int i = 0; i < 4; ++i) ga[i] += 64;
#pragma unroll
    for (int i = 0; i < BRND; ++i) gb[i] += 64;
    if constexpr (BTW > 0) gbt += 64;
    wait_vmcnt<0>();
    __builtin_amdgcn_s_barrier();
  }

  // epilogue: D col = lane&15, row = (lane>>4)*4 + reg
  const int rowb = bm * 256 + wr * 64;
  const int colb = bn * BN + wc * RB;
#pragma unroll
  for (int m = 0; m < 4; ++m)
#pragma unroll
    for (int n = 0; n < NF; ++n)
#pragma unroll
      for (int r = 0; r < 4; ++r) {
        int row = rowb + m * 16 + kh * 4 + r;
        int col = colb + n * 16 + r16;
        float val = acc[m][n][r];
        if constexpr (sizeof(OutT) == 2) C[(size_t)row * N + col] = f2b(val);
        else                             C[(size_t)row * N + col] = val;
      }
}

// ---------- RoPE cos/sin table: tab[pos][i] for pos,i in 0..15 ----------
__global__ void rope_tab_kernel(float2* __restrict__ tab) {
  int t = threadIdx.x;   // 256 threads
  int pos = t >> 4, i = t & 15;
  float inv_freq = __expf(-(float)i * 0.5756462732485115f);  // ln(10000)/16
  float ang = (float)pos * inv_freq;
  float sn, c;
  __sincosf(ang, &sn, &c);
  tab[t] = make_float2(c, sn);
}

// ---------- RoPE(3D) + rearrange ----------
__global__ void rope_kernel(const ushort* __restrict__ qkv,
                            const float2* __restrict__ tab,
                            ushort* __restrict__ Qo, ushort* __restrict__ Ko,
                            ushort* __restrict__ Vt) {
  const int UNITS = 1344;
  int idx = blockIdx.x * 256 + threadIdx.x;
  if (idx >= 8192 * UNITS) return;
  int row = idx / UNITS;
  int unit = idx - row * UNITS;
  int bt = row >> 8, s = row & 255;
  const ushort* qr = qkv + (size_t)row * 2304;
  if (unit < 960) {
    int head, p;
    size_t srcoff;
    ushort* dst;
    if (unit < 768) {            // q
      head = unit / 48; p = unit % 48;
      srcoff = (size_t)head * 96;
      dst = Qo + ((size_t)(bt * 16 + head) * 256 + s) * 96;
    } else {                     // k
      int u = unit - 768;
      head = u / 48; p = u % 48;
      srcoff = 1536 + (size_t)head * 96;
      dst = Ko + ((size_t)(bt * 4 + head) * 256 + s) * 96;
    }
    int seg = p >> 4, i = p & 15;
    int pos = (seg == 0) ? (bt & 15) : ((seg == 1) ? (s >> 4) : (s & 15));
    float2 cs = tab[pos * 16 + i];
    float c = cs.x, sn = cs.y;
    float x1 = b2f(qr[srcoff + seg * 32 + i]);
    float x2 = b2f(qr[srcoff + seg * 32 + i + 16]);
    dst[seg * 32 + i]      = f2b(x1 * c - x2 * sn);
    dst[seg * 32 + i + 16] = f2b(x1 * sn + x2 * c);
  } else {                       // v -> transposed copy
    int u = unit - 960;
    int g = u / 96, d = u - g * 96;
    Vt[((size_t)(bt * 4 + g) * 96 + d) * 256 + s] = qr[1920 + (size_t)g * 96 + d];
  }
}

// ---------- attention v2: one block per (bt, g, qhalf); K/V staged once in LDS ----------
__global__ __launch_bounds__(512, 2) void attn2_kernel(
    const ushort* __restrict__ Q,   // [32][16][256][96]
    const ushort* __restrict__ Kr,  // [32][4][256][96]
    const ushort* __restrict__ Vt,  // [32][4][96][256]
    const int* __restrict__ mask,   // [32][256]
    ushort* __restrict__ Out) {     // [8192][1536] bf16
  __shared__ ushort Ks[256 * 104];
  __shared__ ushort Vs[96 * 264];
  __shared__ ushort Ps[8][16 * 136];
  __shared__ float Mb[256];

  const int b = blockIdx.x;
  const int qt = b & 1;
  const int g = (b >> 1) & 3;
  const int bt = b >> 3;
  const int t = threadIdx.x;
  const int l = t & 63, w = t >> 6;
  const int r16 = l & 15, kh = l >> 4;
  const int h = g * 4 + (w >> 1);
  const int qc = w & 1;

  const ushort* Kp = Kr + (size_t)(bt * 4 + g) * 256 * 96;
  const ushort* Vp = Vt + (size_t)(bt * 4 + g) * 96 * 256;

  {
    int r = t >> 1, ch = t & 1;
#pragma unroll
    for (int j = 0; j < 6; ++j)
      *(short8*)(&Ks[r * 104 + ch * 48 + j * 8]) =
          *(const short8*)(Kp + (size_t)r * 96 + ch * 48 + j * 8);
  }
#pragma unroll
  for (int i = 0; i < 6; ++i) {
    int c = t + i * 512;
    int vr = c >> 5, vc = c & 31;
    *(short8*)(&Vs[vr * 264 + vc * 8]) =
        *(const short8*)(Vp + (size_t)vr * 256 + vc * 8);
  }
  if (t < 256) Mb[t] = mask[bt * 256 + t] ? 0.0f : -1.0e9f;
  __syncthreads();

  const ushort* Qp = Q + ((size_t)(bt * 16 + h) * 256 + qt * 128 + qc * 64) * 96;
  ushort* Pw = &Ps[w][0];
  const float scale = 0.10206207261596575f;  // 1/sqrt(96)

#pragma unroll
  for (int mp = 0; mp < 2; ++mp) {
    const int qb = mp * 32;

    short8 qfA[3], qfB[3];
#pragma unroll
    for (int kc = 0; kc < 3; ++kc) {
      qfA[kc] = *(const short8*)(Qp + (size_t)(qb + r16) * 96 + kc * 32 + kh * 8);
      qfB[kc] = *(const short8*)(Qp + (size_t)(qb + 16 + r16) * 96 + kc * 32 + kh * 8);
    }

    f32x4 scA[16] = {}, scB[16] = {};
#pragma unroll
    for (int f = 0; f < 16; ++f) {
#pragma unroll
      for (int kc = 0; kc < 3; ++kc) {
        short8 kf = *(const short8*)(&Ks[(f * 16 + r16) * 104 + kc * 32 + kh * 8]);
        scA[f] = __builtin_amdgcn_mfma_f32_16x16x32_bf16(qfA[kc], kf, scA[f], 0, 0, 0);
        scB[f] = __builtin_amdgcn_mfma_f32_16x16x32_bf16(qfB[kc], kf, scB[f], 0, 0, 0);
      }
    }

#pragma unroll
    for (int f = 0; f < 16; ++f) {
      float mb = Mb[f * 16 + r16];
#pragma unroll
      for (int r = 0; r < 4; ++r) {
        scA[f][r] = scA[f][r] * scale + mb;
        scB[f][r] = scB[f][r] * scale + mb;
      }
    }

    float invA[4], invB[4];
#pragma unroll
    for (int reg = 0; reg < 4; ++reg) {
      float mxA = -3.0e38f, mxB = -3.0e38f;
#pragma unroll
      for (int f = 0; f < 16; ++f) { mxA = fmaxf(mxA, scA[f][reg]); mxB = fmaxf(mxB, scB[f][reg]); }
      for (int o = 8; o >= 1; o >>= 1) { mxA = fmaxf(mxA, __shfl_xor(mxA, o, 64)); mxB = fmaxf(mxB, __shfl_xor(mxB, o, 64)); }
      float smA = 0.f, smB = 0.f;
#pragma unroll
      for (int f = 0; f < 16; ++f) {
        float pA = __expf(scA[f][reg] - mxA);
        float pB = __expf(scB[f][reg] - mxB);
        scA[f][reg] = pA; scB[f][reg] = pB;
        smA += pA; smB += pB;
      }
      for (int o = 8; o >= 1; o >>= 1) { smA += __shfl_xor(smA, o, 64); smB += __shfl_xor(smB, o, 64); }
      invA[reg] = 1.0f / smA;
      invB[reg] = 1.0f / smB;
    }

    short8 pfA[8], pfB[8];
#pragma unroll
    for (int ck = 0; ck < 2; ++ck) {
#pragma unroll
      for (int f = 0; f < 8; ++f)
#pragma unroll
        for (int reg = 0; reg < 4; ++reg)
          Pw[(kh * 4 + reg) * 136 + f * 16 + r16] = f2b(scA[ck * 8 + f][reg]);
#pragma unroll
      for (int kc = 0; kc < 4; ++kc)
        pfA[ck * 4 + kc] = *(const short8*)(&Pw[r16 * 136 + kc * 32 + kh * 8]);
    }
#pragma unroll
    for (int ck = 0; ck < 2; ++ck) {
#pragma unroll
      for (int f = 0; f < 8; ++f)
#pragma unroll
        for (int reg = 0; reg < 4; ++reg)
          Pw[(kh * 4 + reg) * 136 + f * 16 + r16] = f2b(scB[ck * 8 + f][reg]);
#pragma unroll
      for (int kc = 0; kc < 4; ++kc)
        pfB[ck * 4 + kc] = *(const short8*)(&Pw[r16 * 136 + kc * 32 + kh * 8]);
    }

    f32x4 oA[6] = {}, oB[6] = {};
#pragma unroll
    for (int dt = 0; dt < 6; ++dt) {
#pragma unroll
      for (int kc = 0; kc < 8; ++kc) {
        short8 vf = *(const short8*)(&Vs[(dt * 16 + r16) * 264 + kc * 32 + kh * 8]);
        oA[dt] = __builtin_amdgcn_mfma_f32_16x16x32_bf16(pfA[kc], vf, oA[dt], 0, 0, 0);
        oB[dt] = __builtin_amdgcn_mfma_f32_16x16x32_bf16(pfB[kc], vf, oB[dt], 0, 0, 0);
      }
    }

    const int rbase = bt * 256 + qt * 128 + qc * 64 + qb;
#pragma unroll
    for (int dt = 0; dt < 6; ++dt)
#pragma unroll
      for (int reg = 0; reg < 4; ++reg) {
        int col = h * 96 + dt * 16 + r16;
        Out[(size_t)(rbase + kh * 4 + reg) * 1536 + col]      = f2b(oA[dt][reg] * invA[reg]);
        Out[(size_t)(rbase + 16 + kh * 4 + reg) * 1536 + col] = f2b(oB[dt][reg] * invB[reg]);
      }
  }
}

// ---------- launch ----------
extern "C" void kernel_launch(void* const* d_in, const int* in_sizes, int n_in,
                              void* d_out, int out_size, void* d_ws, size_t ws_size,
                              hipStream_t stream) {
  const float* x     = (const float*)d_in[0];   // [2][16][256][1536]
  const int* pmask   = (const int*)d_in[1];     // [32][256]
  const float* w_qkv = (const float*)d_in[2];   // [2304][1536]
  const float* w_o   = (const float*)d_in[3];   // [1536][1536]
  float* out = (float*)d_out;                   // [8192][1536] f32

  char* ws = (char*)d_ws;
  ushort* Xb  = (ushort*)(ws + 0);          // 8192x1536 bf16
  ushort* Wq  = (ushort*)(ws + 25165824);   // 2304x1536 bf16
  ushort* Wo  = (ushort*)(ws + 32243712);   // 1536x1536 bf16
  ushort* QKV = (ushort*)(ws + 36962304);   // 8192x2304 bf16
  ushort* Qr  = (ushort*)(ws + 74711040);   // 32x16x256x96
  ushort* Kr  = (ushort*)(ws + 99876864);   // 32x4x256x96
  ushort* Vt  = (ushort*)(ws + 106168320);  // 32x4x96x256
  float2* Tab = (float2*)(ws + 112459776);  // 256 x float2 rope table
  ushort* Attn = Xb;                        // reuse Xb slot after gemm1

  cvt_kernel<<<3145728 / 256, 256, 0, stream>>>(x, Xb, 3145728);
  cvt_kernel<<<884736 / 256, 256, 0, stream>>>(w_qkv, Wq, 884736);
  cvt_kernel<<<589824 / 256, 256, 0, stream>>>(w_o, Wo, 589824);
  rope_tab_kernel<<<1, 256, 0, stream>>>(Tab);

  gemm6<288, ushort><<<256, 512, 0, stream>>>(Xb, Wq, QKV, 2304, 1536);

  rope_kernel<<<(8192 * 1344) / 256, 256, 0, stream>>>(QKV, Tab, Qr, Kr, Vt);

  attn2_kernel<<<256, 512, 0, stream>>>(Qr, Kr, Vt, pmask, Attn);

  gemm6<192, float><<<256, 512, 0, stream>>>(Attn, Wo, out, 1536, 1536);
}